// Round 11
// baseline (17.778 us; speedup 1.0000x reference)
//
#include <hip/hip_runtime.h>

#define SCALE 28.853900817779268f   // 20*log2(e)
#define L2E   1.4426950408889634f   // log2(e)
#define M 2048                      // histogram bins over p in [0,1]
#define T 1024                      // threads per block
#define CPC 32                      // blocks per class
#define QB (M/CPC)                  // 64 mk-bins per block (STRIDED: mk = ch + CPC*q)

__device__ __forceinline__ float fexp2(float x){ return __builtin_amdgcn_exp2f(x); }
__device__ __forceinline__ float frcp (float x){ return __builtin_amdgcn_rcpf(x); }
__device__ __forceinline__ float Gfun(int x, float invM){   // g(d)=1/(1+2^(S*d/M)), x=d+2047
  return frcp(1.0f + fexp2(SCALE * (float)(x - (M-1)) * invM));
}

#define WRED64(x) { _Pragma("unroll") for (int _o = 32; _o; _o >>= 1) x += __shfl_down(x, _o, 64); }
#define ALOAD(p) __hip_atomic_load((p), __ATOMIC_RELAXED, __HIP_MEMORY_SCOPE_AGENT)
#define AADD(p,v) __hip_atomic_fetch_add((p),(v), __ATOMIC_RELAXED, __HIP_MEMORY_SCOPE_AGENT)

// 256 blocks = 8 classes x 32 chunks (R10 core). This round attacks the
// SERIAL TAIL: 256 same-line ticket RMWs (~5-10ns each, serialized at the
// memory-side atomic unit) + a 256-word single-block finalize. Replaced by a
// TWO-LEVEL ticket: per-class tickets on 8 separate cachelines (32 RMWs each,
// classes concurrent); the class winner reduces its own 32 gpart entries
// (one coalesced read + shfls, per-class parallel) and overwrites a
// normalized csum[c]/vld[c]; an 8-entry global ticket elects the combiner.
// Same proven regime as R1-10: monotonic tickets (any base -> unique winner
// per launch) + overwrite-only payloads (stale-identical across replays).
// Phase 1 adds half-batch LOAD HOISTING (9 loads in flight before compute).
// Phase-1/2 math bit-identical to R10; integer histogram -> deterministic.
__global__ __launch_bounds__(1024)
void k_fused(const float* __restrict__ logits, const int* __restrict__ tgt,
             float* __restrict__ out, unsigned* __restrict__ gtick,
             unsigned* __restrict__ ctick, float* __restrict__ csum,
             int* __restrict__ vld, float* __restrict__ gpart, int N){
  const int b = blockIdx.x;
  const int c = b >> 5, ch = b & (CPC-1);
  const int tid = threadIdx.x, lane = tid & 63, w = tid >> 6;
  const float invM = 1.0f / (float)M;
  const int s = ch & 1;              // G2 table parity for this block

  __shared__ int    HP[M];           // packed hist: low16 all rows, high16 pos
  __shared__ float2 G2[M];           // G2[e] = {G(2e+s), G(2e+s+1)}
  __shared__ int    Pkc[64];         // compact Pk staging (this block's mk set)
  __shared__ int    wnp[16];
  __shared__ float  rw[16];
  __shared__ int    cflagS, gflagS;

  // setup: zero histogram, build paired difference-sigmoid table (4 trans/thr)
  ((int2*)HP)[tid] = make_int2(0, 0);
  G2[tid]        = make_float2(Gfun(2*tid + s,          invM),
                               Gfun(2*tid + s + 1,      invM));
  G2[tid + 1024] = make_float2(Gfun(2*(tid+1024) + s,   invM),
                               Gfun(2*(tid+1024) + s+1, invM));
  __syncthreads();

  // ---- phase 1: class-c histogram over ALL rows; half-batch load hoist ----
  const float4* l4 = (const float4*)logits;
  if (N == (T<<3)){                  // fast path: exactly 8 rows/thread
    #pragma unroll
    for (int h = 0; h < 2; ++h){
      float4 Ar[4], Br[4]; int tv[4];
      #pragma unroll
      for (int r = 0; r < 4; ++r){   // 9 loads in flight before any compute
        int i = tid + (((h<<2)|r) << 10);
        Ar[r] = l4[2*i]; Br[r] = l4[2*i+1]; tv[r] = tgt[i];
      }
      #pragma unroll
      for (int r = 0; r < 4; ++r){
        float e0=fexp2(Ar[r].x*L2E), e1=fexp2(Ar[r].y*L2E),
              e2=fexp2(Ar[r].z*L2E), e3=fexp2(Ar[r].w*L2E);
        float e4=fexp2(Br[r].x*L2E), e5=fexp2(Br[r].y*L2E),
              e6=fexp2(Br[r].z*L2E), e7=fexp2(Br[r].w*L2E);
        float sm = ((e0+e1)+(e2+e3))+((e4+e5)+(e6+e7));
        float ec = e0;               // static select of class-c exponential
        ec=(c==1)?e1:ec; ec=(c==2)?e2:ec; ec=(c==3)?e3:ec;
        ec=(c==4)?e4:ec; ec=(c==5)?e5:ec; ec=(c==6)?e6:ec; ec=(c==7)?e7:ec;
        float p = ec * frcp(sm);
        int bin = min((int)(p * (float)M), M-1);
        atomicAdd(&HP[bin], 1 + ((tv[r] == c) ? (1 << 16) : 0));
      }
    }
  } else {                           // generic fallback (R10-exact)
    for (int i = tid; i < N; i += T){
      float4 A = l4[2*i], B4 = l4[2*i+1];
      float e0=fexp2(A.x *L2E), e1=fexp2(A.y *L2E), e2=fexp2(A.z *L2E), e3=fexp2(A.w *L2E);
      float e4=fexp2(B4.x*L2E), e5=fexp2(B4.y*L2E), e6=fexp2(B4.z*L2E), e7=fexp2(B4.w*L2E);
      float sm = ((e0+e1)+(e2+e3))+((e4+e5)+(e6+e7));
      float ec = e0;
      ec=(c==1)?e1:ec; ec=(c==2)?e2:ec; ec=(c==3)?e3:ec;
      ec=(c==4)?e4:ec; ec=(c==5)?e5:ec; ec=(c==6)?e6:ec; ec=(c==7)?e7:ec;
      float p = ec * frcp(sm);
      int bin = min((int)(p * (float)M), M-1);
      atomicAdd(&HP[bin], 1 + ((tgt[i] == c) ? (1 << 16) : 0));
    }
  }
  __syncthreads();

  // ---- extraction: thread t owns bins (2t, 2t+1); stage compact Pk ----
  float Hj0, Hj1; int np_part;
  {
    int2 hp = ((const int2*)HP)[tid];
    int p0 = hp.x >> 16, p1 = hp.y >> 16;
    np_part = p0 + p1;
    Hj0 = (float)((hp.x & 0xFFFF) - p0);
    Hj1 = (float)((hp.y & 0xFFFF) - p1);
  }
  if (tid < 64) Pkc[tid] = HP[ch + CPC*tid];   // this block's 64 mk bins
  WRED64(np_part)
  if (lane == 0) wnp[w] = np_part;
  __syncthreads();                   // Pkc + wnp ready

  // ---- phase 2: 64 STRIDED mk-bins; 1 gather + 64 b64 reads per wave ----
  const int jb = ((2046 + ch - s) >> 1) - tid;
  const int pkv = Pkc[lane];         // lane q holds Pk(q); conflict-free b32
  float t0 = 0.f, t1 = 0.f, t2 = 0.f, t3 = 0.f;
  #pragma unroll
  for (int q = 0; q < QB; q += 4){
    #pragma unroll
    for (int u = 0; u < 4; ++u){
      int pq = __builtin_amdgcn_readlane(pkv, q + u);   // VALU broadcast
      float Pk = (float)(pq >> 16);
      float2 gg = G2[jb + 16*(q + u)];                  // one ds_read_b64
      float term = fmaf(Hj0, gg.y, Hj1 * gg.x);
      if (u == 0) t0 = fmaf(Pk, term, t0);
      if (u == 1) t1 = fmaf(Pk, term, t1);
      if (u == 2) t2 = fmaf(Pk, term, t2);
      if (u == 3) t3 = fmaf(Pk, term, t3);
    }
  }
  float tot = (t0 + t1) + (t2 + t3);
  WRED64(tot)
  if (lane == 0) rw[w] = tot;
  __syncthreads();                   // rw visible

  // ---- two-level tail: per-class ticket -> class winner -> global ticket ----
  if (tid == 0){
    float bt = 0.f;
    #pragma unroll
    for (int i = 0; i < 16; ++i) bt += rw[i];
    atomicExch(&gpart[b], bt);       // overwrite -> poison/stale-safe
    __threadfence();                 // release my partial
    unsigned oc = AADD(&ctick[c*16], 1u);   // per-class line (stride 64B)
    cflagS = ((oc & (CPC-1)) == (CPC-1));   // unique class winner per launch
  }
  __syncthreads();
  if (cflagS){
    if (tid == 0) __threadfence();   // acquire class partials
    __syncthreads();
    float sred = 0.f;
    if (tid < CPC){                  // one coalesced 128B gather + shfl tree
      sred = ALOAD(&gpart[c*CPC + tid]);
      #pragma unroll
      for (int o = 16; o; o >>= 1) sred += __shfl_down(sred, o, 32);
    }
    if (tid == 0){
      int snp = 0;
      #pragma unroll
      for (int i = 0; i < 16; ++i) snp += wnp[i];   // np: identical in class
      int nn = N - snp;
      bool v = (snp > 0 && nn > 0);
      float tc = v ? sred / ((float)snp * (float)nn) : 0.f;
      atomicExch(&csum[c], tc);      // normalized class term (overwrite)
      atomicExch(&vld[c],  v ? 1 : 0);
      __threadfence();               // release
      unsigned og = AADD(gtick, 1u); // 8 arrivals/launch
      gflagS = ((og & 7u) == 7u);    // unique global winner
    }
  } else if (tid == 0) gflagS = 0;
  __syncthreads();
  if (!gflagS) return;

  // ---- global combine (winner block; fixed order -> deterministic) ----
  if (tid == 0) __threadfence();     // acquire
  __syncthreads();
  if (tid < 8){
    float t = ALOAD(&csum[tid]);
    float f = (float)ALOAD(&vld[tid]);
    #pragma unroll
    for (int o = 4; o; o >>= 1){
      t += __shfl_down(t, o, 8);
      f += __shfl_down(f, o, 8);
    }
    if (tid == 0) out[0] = (f > 0.f) ? (1.0f - t / f) : 0.0f;
  }
}

extern "C" void kernel_launch(void* const* d_in, const int* in_sizes, int n_in,
                              void* d_out, int out_size, void* d_ws, size_t ws_size,
                              hipStream_t stream) {
    const float* logits = (const float*)d_in[0];
    const int*   tgt    = (const int*)d_in[1];
    float* out = (float*)d_out;
    int N = in_sizes[1];

    unsigned* ws    = (unsigned*)d_ws;
    unsigned* gtick = ws;                              // [0] global ticket
    unsigned* ctick = ws + 16;                         // [16+16c] per-class tickets
    float*    csum  = (float*)(ws + 160);              // [160..167] class terms
    int*      vld   = (int*)  (ws + 168);              // [168..175] validity
    float*    gpart = (float*)(ws + 192);              // [192..447] block partials

    k_fused<<<8*CPC, T, 0, stream>>>(logits, tgt, out, gtick, ctick,
                                     csum, vld, gpart, N);
}

// Round 12
// 17.015 us; speedup vs baseline: 1.0448x; 1.0448x over previous
//
#include <hip/hip_runtime.h>

#define SCALE 28.853900817779268f   // 20*log2(e)
#define L2E   1.4426950408889634f   // log2(e)
#define M 2048                      // histogram bins over p in [0,1]
#define T 1024                      // threads per block
#define CPC 32                      // blocks per class
#define QB (M/CPC)                  // 64 mk-bins per block (STRIDED: mk = ch + CPC*q)

__device__ __forceinline__ float fexp2(float x){ return __builtin_amdgcn_exp2f(x); }
__device__ __forceinline__ float frcp (float x){ return __builtin_amdgcn_rcpf(x); }
__device__ __forceinline__ float Gfun(int x, float invM){   // g(d)=1/(1+2^(S*d/M)), x=d+2047
  return frcp(1.0f + fexp2(SCALE * (float)(x - (M-1)) * invM));
}

#define WRED64(x) { _Pragma("unroll") for (int _o = 32; _o; _o >>= 1) x += __shfl_down(x, _o, 64); }
#define ALOAD(p) __hip_atomic_load((p), __ATOMIC_RELAXED, __HIP_MEMORY_SCOPE_AGENT)

// EXACT revert to R10 (verified 17.20us best). R11's two bundled changes both
// regressed: load-hoist (+40 VGPR live range at 1024 thr) and two-level tail
// (longer dependency chain after the slowest block: winner's fence->gather->
// reduce->exch->fence->RMW rounds serialize; the flat 256-RMW ticket is
// fire-and-forget for all non-winners and memory-side atomics pipeline
// same-line adds). Tested-and-refuted alternatives now cover every remaining
// term: R6 global sharing, R9 redundancy reduction, R11 tail/hoist. Phase 2
// LDS-minimization (this kernel) was the one real structural win.
__global__ __launch_bounds__(1024)
void k_fused(const float* __restrict__ logits, const int* __restrict__ tgt,
             float* __restrict__ out, unsigned* __restrict__ ticket,
             float* __restrict__ gpart, int* __restrict__ ccnt, int N){
  const int b = blockIdx.x, NB = (int)gridDim.x;
  const int c = b >> 5, ch = b & (CPC-1);
  const int tid = threadIdx.x, lane = tid & 63, w = tid >> 6;
  const float invM = 1.0f / (float)M;
  const int s = ch & 1;              // table parity for this block

  __shared__ int    HP[M];           // packed hist: low16 all rows, high16 pos
  __shared__ float2 G2[M];           // G2[e] = {G(2e+s), G(2e+s+1)}
  __shared__ int    Pkc[64];         // compact Pk staging (this block's mk set)
  __shared__ int    wnp[16];
  __shared__ float  rw[16];
  __shared__ float  scs[8];
  __shared__ int    lastflag;

  // setup: zero histogram, build paired difference-sigmoid table (4 trans/thr)
  ((int2*)HP)[tid] = make_int2(0, 0);
  G2[tid]        = make_float2(Gfun(2*tid + s,          invM),
                               Gfun(2*tid + s + 1,      invM));
  G2[tid + 1024] = make_float2(Gfun(2*(tid+1024) + s,   invM),
                               Gfun(2*(tid+1024) + s+1, invM));
  __syncthreads();

  // ---- phase 1: class-c histogram over ALL rows ----
  const float4* l4 = (const float4*)logits;
  #pragma unroll 2
  for (int i = tid; i < N; i += T){
    float4 A = l4[2*i], B4 = l4[2*i+1];
    float e0=fexp2(A.x *L2E), e1=fexp2(A.y *L2E), e2=fexp2(A.z *L2E), e3=fexp2(A.w *L2E);
    float e4=fexp2(B4.x*L2E), e5=fexp2(B4.y*L2E), e6=fexp2(B4.z*L2E), e7=fexp2(B4.w*L2E);
    float sm = ((e0+e1)+(e2+e3))+((e4+e5)+(e6+e7));
    float ec = e0;                   // static select of class-c exponential
    ec=(c==1)?e1:ec; ec=(c==2)?e2:ec; ec=(c==3)?e3:ec;
    ec=(c==4)?e4:ec; ec=(c==5)?e5:ec; ec=(c==6)?e6:ec; ec=(c==7)?e7:ec;
    float p = ec * frcp(sm);
    int bin = min((int)(p * (float)M), M-1);
    int inc = 1 + ((tgt[i] == c) ? (1 << 16) : 0);
    atomicAdd(&HP[bin], inc);        // LDS, integer -> deterministic
  }
  __syncthreads();

  // ---- extraction: thread t owns bins (2t, 2t+1); stage compact Pk ----
  float Hj0, Hj1; int np_part;
  {
    int2 hp = ((const int2*)HP)[tid];
    int p0 = hp.x >> 16, p1 = hp.y >> 16;
    np_part = p0 + p1;
    Hj0 = (float)((hp.x & 0xFFFF) - p0);
    Hj1 = (float)((hp.y & 0xFFFF) - p1);
  }
  if (tid < 64) Pkc[tid] = HP[ch + CPC*tid];   // this block's 64 mk bins
  WRED64(np_part)
  if (lane == 0) wnp[w] = np_part;
  __syncthreads();                   // Pkc ready (wnp also covered)

  // ---- phase 2: 64 STRIDED mk-bins; 1 gather + 64 b64 reads per wave ----
  // term (q, mj): d = ch+32q-mj; mj0=2t -> x0 = d0+2047; mj1=2t+1 -> x1 = x0-1
  // {x1,x0} = {2j+s, 2j+s+1},  j = (2046+ch-s)/2 + 16q - t
  const int jb = ((2046 + ch - s) >> 1) - tid;
  const int pkv = Pkc[lane];         // lane q holds Pk(q); conflict-free b32
  float t0 = 0.f, t1 = 0.f, t2 = 0.f, t3 = 0.f;
  #pragma unroll
  for (int q = 0; q < QB; q += 4){
    #pragma unroll
    for (int u = 0; u < 4; ++u){
      int pq = __builtin_amdgcn_readlane(pkv, q + u);   // VALU broadcast
      float Pk = (float)(pq >> 16);
      float2 gg = G2[jb + 16*(q + u)];                  // one ds_read_b64
      float term = fmaf(Hj0, gg.y, Hj1 * gg.x);         // gg.y=g(mj0), gg.x=g(mj1)
      if (u == 0) t0 = fmaf(Pk, term, t0);
      if (u == 1) t1 = fmaf(Pk, term, t1);
      if (u == 2) t2 = fmaf(Pk, term, t2);
      if (u == 3) t3 = fmaf(Pk, term, t3);
    }
  }
  float tot = (t0 + t1) + (t2 + t3);
  WRED64(tot)
  if (lane == 0) rw[w] = tot;
  __syncthreads();                   // rw visible
  if (tid == 0){
    float bt = 0.f;
    #pragma unroll
    for (int i = 0; i < 16; ++i) bt += rw[i];
    atomicExch(&gpart[b], bt);       // overwrite -> poison/stale-safe
    if (ch == 0){                    // one writer/class; np identical in all
      int snp = 0;
      #pragma unroll
      for (int i = 0; i < 16; ++i) snp += wnp[i];
      atomicExch(&ccnt[c], snp);
    }
    __threadfence();                 // release
    unsigned old = atomicAdd(ticket, 1u);  // persistent mod-NB ticket
    lastflag = ((old % (unsigned)NB) == (unsigned)(NB - 1));
  }
  __syncthreads();
  if (!lastflag) return;

  // ---- finalize (last block; fixed order -> deterministic) ----
  if (tid == 0) __threadfence();     // acquire
  __syncthreads();
  if (tid < 256){
    int c2 = tid >> 5, l = tid & 31;
    float sp = ALOAD(&gpart[c2*CPC + l]);  // agent-scope load (no RMW)
    #pragma unroll
    for (int o = 16; o; o >>= 1) sp += __shfl_down(sp, o, 32);
    if (l == 0) scs[c2] = sp;
  }
  __syncthreads();
  if (tid < 8){
    int np = ALOAD(&ccnt[tid]);
    int nn = N - np;
    bool valid = (np > 0 && nn > 0);
    float t = valid ? scs[tid] / ((float)np * (float)nn) : 0.f;
    float f = valid ? 1.f : 0.f;
    #pragma unroll
    for (int o = 4; o; o >>= 1){
      t += __shfl_down(t, o, 8);
      f += __shfl_down(f, o, 8);
    }
    if (tid == 0) out[0] = (f > 0.f) ? (1.0f - t / f) : 0.0f;
  }
}

extern "C" void kernel_launch(void* const* d_in, const int* in_sizes, int n_in,
                              void* d_out, int out_size, void* d_ws, size_t ws_size,
                              hipStream_t stream) {
    const float* logits = (const float*)d_in[0];
    const int*   tgt    = (const int*)d_in[1];
    float* out = (float*)d_out;
    int N = in_sizes[1];

    unsigned* ticket = (unsigned*)d_ws;                // [0] persistent mod-NB
    float* gpart = (float*)d_ws + 32;                  // [32..287] block partials
    int*   ccnt  = (int*)((float*)d_ws + 288);         // [288..295]

    k_fused<<<8*CPC, T, 0, stream>>>(logits, tgt, out, ticket, gpart, ccnt, N);
}

// Round 13
// 16.724 us; speedup vs baseline: 1.0630x; 1.0174x over previous
//
#include <hip/hip_runtime.h>

#define SCALE 28.853900817779268f   // 20*log2(e)
#define L2E   1.4426950408889634f   // log2(e)
#define M 2048                      // histogram bins over p in [0,1]
#define T 1024                      // threads per block
#define CPC 32                      // blocks per class
#define QB (M/CPC)                  // 64 mk-bins per block (STRIDED: mk = ch + CPC*q)

__device__ __forceinline__ float fexp2(float x){ return __builtin_amdgcn_exp2f(x); }
__device__ __forceinline__ float frcp (float x){ return __builtin_amdgcn_rcpf(x); }
__device__ __forceinline__ float Gfun(int x, float invM){   // g(d)=1/(1+2^(S*d/M)), x=d+2047
  return frcp(1.0f + fexp2(SCALE * (float)(x - (M-1)) * invM));
}

#define WRED64(x) { _Pragma("unroll") for (int _o = 32; _o; _o >>= 1) x += __shfl_down(x, _o, 64); }
#define ALOAD(p) __hip_atomic_load((p), __ATOMIC_RELAXED, __HIP_MEMORY_SCOPE_AGENT)

// R10/R12 core (verified 17.0-17.2us) + ONE change: the phase-2 zero-skip is
// BACK, but gated on a REGISTER (readlane of Pkc staged in VGPRs) instead of
// R3's uniform LDS load -> the branch is a cheap scalar s_cmp/s_cbranch with
// no 120cy LDS-latency chain (the reason R10 dropped it). ~55-65% of mk-bins
// have zero positives; skipping removes their ds_read_b64 + fmas, halving
// phase-2 LDS-pipe pressure (16 waves contend on one pipe). Skipped terms are
// exactly fmaf(0,term,acc)==acc -> bit-identical output to R12.
// Evidence note (R12): dur_us ~= kernel time (R6: 42.6 vs 46.6 profiled) and
// cycle cuts pay 1.5-2.5x the 2.4GHz prediction -> low effective shader clock;
// remaining cycle terms still matter.
__global__ __launch_bounds__(1024)
void k_fused(const float* __restrict__ logits, const int* __restrict__ tgt,
             float* __restrict__ out, unsigned* __restrict__ ticket,
             float* __restrict__ gpart, int* __restrict__ ccnt, int N){
  const int b = blockIdx.x, NB = (int)gridDim.x;
  const int c = b >> 5, ch = b & (CPC-1);
  const int tid = threadIdx.x, lane = tid & 63, w = tid >> 6;
  const float invM = 1.0f / (float)M;
  const int s = ch & 1;              // table parity for this block

  __shared__ int    HP[M];           // packed hist: low16 all rows, high16 pos
  __shared__ float2 G2[M];           // G2[e] = {G(2e+s), G(2e+s+1)}
  __shared__ int    Pkc[64];         // compact Pk staging (this block's mk set)
  __shared__ int    wnp[16];
  __shared__ float  rw[16];
  __shared__ float  scs[8];
  __shared__ int    lastflag;

  // setup: zero histogram, build paired difference-sigmoid table (4 trans/thr)
  ((int2*)HP)[tid] = make_int2(0, 0);
  G2[tid]        = make_float2(Gfun(2*tid + s,          invM),
                               Gfun(2*tid + s + 1,      invM));
  G2[tid + 1024] = make_float2(Gfun(2*(tid+1024) + s,   invM),
                               Gfun(2*(tid+1024) + s+1, invM));
  __syncthreads();

  // ---- phase 1: class-c histogram over ALL rows ----
  const float4* l4 = (const float4*)logits;
  #pragma unroll 2
  for (int i = tid; i < N; i += T){
    float4 A = l4[2*i], B4 = l4[2*i+1];
    float e0=fexp2(A.x *L2E), e1=fexp2(A.y *L2E), e2=fexp2(A.z *L2E), e3=fexp2(A.w *L2E);
    float e4=fexp2(B4.x*L2E), e5=fexp2(B4.y*L2E), e6=fexp2(B4.z*L2E), e7=fexp2(B4.w*L2E);
    float sm = ((e0+e1)+(e2+e3))+((e4+e5)+(e6+e7));
    float ec = e0;                   // static select of class-c exponential
    ec=(c==1)?e1:ec; ec=(c==2)?e2:ec; ec=(c==3)?e3:ec;
    ec=(c==4)?e4:ec; ec=(c==5)?e5:ec; ec=(c==6)?e6:ec; ec=(c==7)?e7:ec;
    float p = ec * frcp(sm);
    int bin = min((int)(p * (float)M), M-1);
    int inc = 1 + ((tgt[i] == c) ? (1 << 16) : 0);
    atomicAdd(&HP[bin], inc);        // LDS, integer -> deterministic
  }
  __syncthreads();

  // ---- extraction: thread t owns bins (2t, 2t+1); stage compact Pk ----
  float Hj0, Hj1; int np_part;
  {
    int2 hp = ((const int2*)HP)[tid];
    int p0 = hp.x >> 16, p1 = hp.y >> 16;
    np_part = p0 + p1;
    Hj0 = (float)((hp.x & 0xFFFF) - p0);
    Hj1 = (float)((hp.y & 0xFFFF) - p1);
  }
  if (tid < 64) Pkc[tid] = HP[ch + CPC*tid];   // this block's 64 mk bins
  WRED64(np_part)
  if (lane == 0) wnp[w] = np_part;
  __syncthreads();                   // Pkc ready (wnp also covered)

  // ---- phase 2: 64 STRIDED mk-bins; register-gated zero-skip ----
  // term (q, mj): d = ch+32q-mj; mj0=2t -> x0 = d0+2047; mj1=2t+1 -> x1 = x0-1
  // {x1,x0} = {2j+s, 2j+s+1},  j = (2046+ch-s)/2 + 16q - t
  const int jb = ((2046 + ch - s) >> 1) - tid;
  const int pkv = Pkc[lane];         // lane q holds Pk(q); conflict-free b32
  float t0 = 0.f, t1 = 0.f, t2 = 0.f, t3 = 0.f;
  #pragma unroll
  for (int q = 0; q < QB; q += 4){
    #pragma unroll
    for (int u = 0; u < 4; ++u){
      int pq = __builtin_amdgcn_readlane(pkv, q + u) >> 16;  // scalar broadcast
      if (pq != 0){                  // wave-uniform scalar branch, no LDS chain
        float Pk = (float)pq;
        float2 gg = G2[jb + 16*(q + u)];                // one ds_read_b64
        float term = fmaf(Hj0, gg.y, Hj1 * gg.x);       // gg.y=g(mj0), gg.x=g(mj1)
        if (u == 0) t0 = fmaf(Pk, term, t0);
        if (u == 1) t1 = fmaf(Pk, term, t1);
        if (u == 2) t2 = fmaf(Pk, term, t2);
        if (u == 3) t3 = fmaf(Pk, term, t3);
      }
    }
  }
  float tot = (t0 + t1) + (t2 + t3);
  WRED64(tot)
  if (lane == 0) rw[w] = tot;
  __syncthreads();                   // rw visible
  if (tid == 0){
    float bt = 0.f;
    #pragma unroll
    for (int i = 0; i < 16; ++i) bt += rw[i];
    atomicExch(&gpart[b], bt);       // overwrite -> poison/stale-safe
    if (ch == 0){                    // one writer/class; np identical in all
      int snp = 0;
      #pragma unroll
      for (int i = 0; i < 16; ++i) snp += wnp[i];
      atomicExch(&ccnt[c], snp);
    }
    __threadfence();                 // release
    unsigned old = atomicAdd(ticket, 1u);  // persistent mod-NB ticket
    lastflag = ((old % (unsigned)NB) == (unsigned)(NB - 1));
  }
  __syncthreads();
  if (!lastflag) return;

  // ---- finalize (last block; fixed order -> deterministic) ----
  if (tid == 0) __threadfence();     // acquire
  __syncthreads();
  if (tid < 256){
    int c2 = tid >> 5, l = tid & 31;
    float sp = ALOAD(&gpart[c2*CPC + l]);  // agent-scope load (no RMW)
    #pragma unroll
    for (int o = 16; o; o >>= 1) sp += __shfl_down(sp, o, 32);
    if (l == 0) scs[c2] = sp;
  }
  __syncthreads();
  if (tid < 8){
    int np = ALOAD(&ccnt[tid]);
    int nn = N - np;
    bool valid = (np > 0 && nn > 0);
    float t = valid ? scs[tid] / ((float)np * (float)nn) : 0.f;
    float f = valid ? 1.f : 0.f;
    #pragma unroll
    for (int o = 4; o; o >>= 1){
      t += __shfl_down(t, o, 8);
      f += __shfl_down(f, o, 8);
    }
    if (tid == 0) out[0] = (f > 0.f) ? (1.0f - t / f) : 0.0f;
  }
}

extern "C" void kernel_launch(void* const* d_in, const int* in_sizes, int n_in,
                              void* d_out, int out_size, void* d_ws, size_t ws_size,
                              hipStream_t stream) {
    const float* logits = (const float*)d_in[0];
    const int*   tgt    = (const int*)d_in[1];
    float* out = (float*)d_out;
    int N = in_sizes[1];

    unsigned* ticket = (unsigned*)d_ws;                // [0] persistent mod-NB
    float* gpart = (float*)d_ws + 32;                  // [32..287] block partials
    int*   ccnt  = (int*)((float*)d_ws + 288);         // [288..295]

    k_fused<<<8*CPC, T, 0, stream>>>(logits, tgt, out, ticket, gpart, ccnt, N);
}